// Round 4
// baseline (978.367 us; speedup 1.0000x reference)
//
#include <hip/hip_runtime.h>
#include <hip/hip_fp16.h>
#include <math.h>

// ---------------- problem constants ----------------
#define T_LEN 16384
#define D_IN  2048
#define H_GRU 256
#define G3    768      // 3*H
#define NFRM  8
#define NCLS  2

// GRU chunking: CHUNK=32 payload, WARM=48 warmup, BQ=4 chunks/block.
#define CHUNK 32
#define WARM  48
#define GSTEPS (WARM + CHUNK)           // 80
#define BQ    4
#define NCHUNK (T_LEN / CHUNK)          // 512 per dir
#define GRU_BLOCKS (NCHUNK / BQ)        // 128 per dir

typedef _Float16 f16x8 __attribute__((ext_vector_type(8)));
typedef float    f32x4 __attribute__((ext_vector_type(4)));

// ---------------- workspace layout (in floats) ----------------
static const size_t OFF_GXF = 0;
static const size_t OFF_GXB = OFF_GXF + (size_t)T_LEN * G3;
static const size_t OFF_H   = OFF_GXB + (size_t)T_LEN * G3;
static const size_t OFF_BIA = OFF_H   + (size_t)T_LEN * 512;    // folded biases 2*768
static const size_t OFF_SC  = OFF_BIA + 2 * G3;
static const size_t OFF_WPF = OFF_SC  + (size_t)T_LEN;          // f16x8[48*8*64] = 393216 B
static const size_t OFF_WPB = OFF_WPF + (size_t)G3 * H_GRU / 2;
static const size_t OFF_SEL = OFF_WPB + (size_t)G3 * H_GRU / 2; // 8 int idx + 8 float w
static const size_t OFF_CH  = OFF_SEL + 16;                     // 256 floats hidden
// total ~134 MB
// NOTE: B16 (fp16 W_ih_cat, 1536x2048 = 6.3 MB) lives in the Hbuf region
// (ws + OFF_H) during the GEMM; Hbuf is only written by the GRU afterwards.

__device__ __forceinline__ float fsig(float x) {
    return __builtin_amdgcn_rcpf(1.f + __expf(-x));
}
__device__ __forceinline__ float ftanh(float x) {
    float e = __expf(2.f * x);
    return 1.f - 2.f * __builtin_amdgcn_rcpf(e + 1.f);
}

__device__ __forceinline__ f16x8 pack8(const f32x4 lo, const f32x4 hi) {
    f16x8 r;
    r[0] = (_Float16)lo[0]; r[1] = (_Float16)lo[1];
    r[2] = (_Float16)lo[2]; r[3] = (_Float16)lo[3];
    r[4] = (_Float16)hi[0]; r[5] = (_Float16)hi[1];
    r[6] = (_Float16)hi[2]; r[7] = (_Float16)hi[3];
    return r;
}

// ---------------- fold b_hh (r,z gates) into the input-projection bias ----------------
__global__ void bias_fold_kernel(const float* __restrict__ bi0, const float* __restrict__ bh0,
                                 const float* __restrict__ bi1, const float* __restrict__ bh1,
                                 float* __restrict__ o0, float* __restrict__ o1) {
    int t = blockIdx.x * 256 + threadIdx.x;
    if (t < G3) {
        float a0 = bi0[t], a1 = bi1[t];
        if (t < 512) { a0 += bh0[t]; a1 += bh1[t]; }
        o0[t] = a0; o1[t] = a1;
    }
}

// ---------------- convert W_ih_{f,b} (fp32) -> B16 fp16 [1536][2048] ----------------
__global__ __launch_bounds__(256) void cvt_w_kernel(const float* __restrict__ Wf,
                                                    const float* __restrict__ Wb,
                                                    __half* __restrict__ B16) {
    const float* __restrict__ src = blockIdx.y ? Wb : Wf;
    __half* __restrict__ dst = B16 + (size_t)blockIdx.y * G3 * D_IN;
    const int i = blockIdx.x * 256 + threadIdx.x;    // 8 floats per thread
    float4 a = *(const float4*)&src[(size_t)i * 8];
    float4 b = *(const float4*)&src[(size_t)i * 8 + 4];
    __half2 h[4];
    h[0] = __float22half2_rn(make_float2(a.x, a.y));
    h[1] = __float22half2_rn(make_float2(a.z, a.w));
    h[2] = __float22half2_rn(make_float2(b.x, b.y));
    h[3] = __float22half2_rn(make_float2(b.z, b.w));
    *(float4*)&dst[(size_t)i * 8] = *(float4*)h;
}

// ---------------- pack W_hh into MFMA A-fragment order ----------------
__global__ void pack_whh_mfma_kernel(const float* __restrict__ W0,
                                     const float* __restrict__ W1,
                                     f16x8* __restrict__ P0,
                                     f16x8* __restrict__ P1) {
    const float* W = blockIdx.y ? W1 : W0;
    f16x8* P = blockIdx.y ? P1 : P0;
    int tc = blockIdx.x;             // 0..383 = t*8 + c
    int l = threadIdx.x;             // 0..63
    int t = tc >> 3, c = tc & 7;
    int m = t * 16 + (l & 15);
    int k = c * 32 + (l >> 4) * 8;
    const float* src = W + (size_t)m * H_GRU + k;
    f16x8 v;
#pragma unroll
    for (int j = 0; j < 8; ++j) v[j] = (_Float16)src[j];
    P[(size_t)tc * 64 + l] = v;
}

// ---------------- gx GEMM: direct global->register MFMA (no LDS, no barriers) ----------------
// C[M][1536] = A[M][2048](f32) @ B16[1536][2048]^T + bias, split to gx_f / gx_b.
// 128x128 tile, 4 waves (2M x 2N). Each wave loads its own MFMA fragments
// straight from global: B16 is fragment-ready fp16 (one f16x8/lane/frag);
// A loads 2x f32x4 + in-register pack (RN). Per-iter working set (A 16 KB +
// B 8 KB, shared by 12 blocks/XCD via swizzle) is L1/L2-resident, so the x2
// intra-block fragment redundancy is cache-served. Waves free-run; latency
// hidden by 12 waves/CU of TLP. Zero LDS -> zero bank conflicts, zero
// barrier drains (the measured killer of rounds 1-3).
#define GXBK 32
__global__ __launch_bounds__(256, 3) void gemm_gx_kernel(
    const float* __restrict__ A,      // features [16384][2048] f32
    const __half* __restrict__ B16,   // [1536][2048] f16
    const float* __restrict__ biaf, const float* __restrict__ biab,
    float* __restrict__ Cf, float* __restrict__ Cb) {
    const int tid  = threadIdx.x;
    const int lane = tid & 63;
    const int wave = tid >> 6;
    const int lm   = lane & 15;
    const int lk   = lane >> 4;
    const int mw   = wave & 1;
    const int nw   = wave >> 1;

    // XCD swizzle (1536 % 8 == 0 -> bijective) + nt-fast decode so 12
    // consecutive blocks on one XCD share the A-tile in L2.
    const int wg = blockIdx.x;
    const int id = (wg & 7) * (1536 / 8) + (wg >> 3);
    const int mt = id / 12;
    const int nt = id - mt * 12;
    const int bm  = mt * 128;
    const int bnt = nt * 128;                 // row offset into B16 [0..1535]

    const float* __restrict__ bias;
    float* __restrict__ C;
    int bn_local;
    if (nt < 6) { C = Cf; bias = biaf; bn_local = bnt; }
    else        { C = Cb; bias = biab; bn_local = bnt - 768; }

    // per-lane fragment bases: afr[tm] lane -> row bm+64mw+16tm+lm, k lk*8
    const float*  gA = A   + (size_t)(bm  + 64 * mw + lm) * D_IN + lk * 8;
    const __half* gB = B16 + (size_t)(bnt + 64 * nw + lm) * D_IN + lk * 8;

    f32x4 acc[4][4];
#pragma unroll
    for (int a = 0; a < 4; ++a)
#pragma unroll
        for (int b = 0; b < 4; ++b) acc[a][b] = (f32x4)0.f;

#pragma unroll 1
    for (int k0 = 0; k0 < D_IN; k0 += GXBK) {
        f16x8 afr[4], bfr[4];
#pragma unroll
        for (int tm = 0; tm < 4; ++tm) {
            const float* p = gA + (size_t)(16 * tm) * D_IN + k0;
            f32x4 lo = *(const f32x4*)p;
            f32x4 hi = *(const f32x4*)(p + 4);
            afr[tm] = pack8(lo, hi);
        }
#pragma unroll
        for (int tn = 0; tn < 4; ++tn)
            bfr[tn] = *(const f16x8*)(gB + (size_t)(16 * tn) * D_IN + k0);
#pragma unroll
        for (int tm = 0; tm < 4; ++tm)
#pragma unroll
            for (int tn = 0; tn < 4; ++tn)
                acc[tm][tn] = __builtin_amdgcn_mfma_f32_16x16x32_f16(
                    afr[tm], bfr[tn], acc[tm][tn], 0, 0, 0);
    }

#pragma unroll
    for (int tm = 0; tm < 4; ++tm) {
#pragma unroll
        for (int tn = 0; tn < 4; ++tn) {
            int gn = bn_local + 64 * nw + 16 * tn + lm;
            float bb = bias[gn];
#pragma unroll
            for (int reg = 0; reg < 4; ++reg) {
                int gm = bm + 64 * mw + 16 * tm + lk * 4 + reg;
                C[(size_t)gm * G3 + gn] = acc[tm][tn][reg] + bb;
            }
        }
    }
}

// ---------------- scorer: scores = relu(Hbuf @ Ws1^T + bs1) @ Ws2^T + bs2 ----------------
// 64x64 tile over M, N=64 fixed (whole Ws1), layer-2 dot fused in epilogue.
#define BM 64
#define BN 64
#define BK 32
__global__ __launch_bounds__(256) void scorer_kernel(
    const float* __restrict__ A,       // Hbuf [T][512]
    const float* __restrict__ B,       // Ws1 [64][512]
    const float* __restrict__ bias,    // bs1 [64]
    const float* __restrict__ Ws2,     // [64]
    const float* __restrict__ bs2,     // [1]
    float* __restrict__ sc, float* __restrict__ outs,
    int M, int N, int K) {
    __shared__ __align__(16) float As[BK][BM + 4];
    __shared__ __align__(16) float Bs[BK][BN + 4];

    const int tid = threadIdx.x;
    const int bm = blockIdx.x * BM;
    const int kk8 = tid & 7;
    const int r32 = tid >> 3;
    const int tx = tid & 15;
    const int ty = tid >> 4;

    float acc[4][4];
#pragma unroll
    for (int a = 0; a < 4; ++a)
#pragma unroll
        for (int b = 0; b < 4; ++b) acc[a][b] = 0.f;

    for (int k0 = 0; k0 < K; k0 += BK) {
        float4 a0 = *(const float4*)&A[(size_t)(bm + r32) * K + k0 + kk8 * 4];
        float4 a1 = *(const float4*)&A[(size_t)(bm + r32 + 32) * K + k0 + kk8 * 4];
        float4 b0 = *(const float4*)&B[(size_t)(r32) * K + k0 + kk8 * 4];
        float4 b1 = *(const float4*)&B[(size_t)(r32 + 32) * K + k0 + kk8 * 4];
        __syncthreads();
        As[kk8 * 4 + 0][r32] = a0.x; As[kk8 * 4 + 1][r32] = a0.y;
        As[kk8 * 4 + 2][r32] = a0.z; As[kk8 * 4 + 3][r32] = a0.w;
        As[kk8 * 4 + 0][r32 + 32] = a1.x; As[kk8 * 4 + 1][r32 + 32] = a1.y;
        As[kk8 * 4 + 2][r32 + 32] = a1.z; As[kk8 * 4 + 3][r32 + 32] = a1.w;
        Bs[kk8 * 4 + 0][r32] = b0.x; Bs[kk8 * 4 + 1][r32] = b0.y;
        Bs[kk8 * 4 + 2][r32] = b0.z; Bs[kk8 * 4 + 3][r32] = b0.w;
        Bs[kk8 * 4 + 0][r32 + 32] = b1.x; Bs[kk8 * 4 + 1][r32 + 32] = b1.y;
        Bs[kk8 * 4 + 2][r32 + 32] = b1.z; Bs[kk8 * 4 + 3][r32 + 32] = b1.w;
        __syncthreads();
#pragma unroll 8
        for (int kk = 0; kk < BK; ++kk) {
            float4 av = *(const float4*)&As[kk][ty * 4];
            float4 bv = *(const float4*)&Bs[kk][tx * 4];
            acc[0][0] += av.x * bv.x; acc[0][1] += av.x * bv.y; acc[0][2] += av.x * bv.z; acc[0][3] += av.x * bv.w;
            acc[1][0] += av.y * bv.x; acc[1][1] += av.y * bv.y; acc[1][2] += av.y * bv.z; acc[1][3] += av.y * bv.w;
            acc[2][0] += av.z * bv.x; acc[2][1] += av.z * bv.y; acc[2][2] += av.z * bv.z; acc[2][3] += av.z * bv.w;
            acc[3][0] += av.w * bv.x; acc[3][1] += av.w * bv.y; acc[3][2] += av.w * bv.z; acc[3][3] += av.w * bv.w;
        }
    }

    // fused layer 2: per-thread partial dot over its 4 cols, reduce across tx group
    float4 bvv = *(const float4*)&bias[tx * 4];
    float4 w2  = *(const float4*)&Ws2[tx * 4];
    const float b2 = bs2[0];
#pragma unroll
    for (int im = 0; im < 4; ++im) {
        float s = fmaxf(acc[im][0] + bvv.x, 0.f) * w2.x
                + fmaxf(acc[im][1] + bvv.y, 0.f) * w2.y
                + fmaxf(acc[im][2] + bvv.z, 0.f) * w2.z
                + fmaxf(acc[im][3] + bvv.w, 0.f) * w2.w;
#pragma unroll
        for (int off = 1; off < 16; off <<= 1) s += __shfl_xor(s, off);
        if (tx == 0) {
            int m = bm + ty * 4 + im;
            float sval = s + b2;
            sc[m] = sval;
            outs[m] = sval;
        }
    }
}

// ---------------- chunked BiGRU v5: W-resident MFMA, 1024-thread blocks ----------------
// 16 waves, wave wv owns 3 row-tiles (48 gate rows) of W in registers (96 VGPRs).
// Epilogue: thread (grp=tid>>8, i=tid&255) owns chunk grp, row i (1 state/thread).
#define HPAD 272
__global__ __launch_bounds__(1024, 4) void gru_v5_kernel(
    const float* __restrict__ gx0, const float* __restrict__ gx1,
    const f16x8* __restrict__ Wk0, const f16x8* __restrict__ Wk1,
    const float* __restrict__ bh0, const float* __restrict__ bh1,
    float* __restrict__ Hbuf) {
    const int dir = blockIdx.y;
    const float* __restrict__ gx = dir ? gx1 : gx0;
    const f16x8* __restrict__ Wk = dir ? Wk1 : Wk0;
    const float* __restrict__ bh = dir ? bh1 : bh0;
    const int col_off = dir * 256;

    const int tid  = threadIdx.x;
    const int lane = tid & 63;
    const int wv   = tid >> 6;       // wave 0..15
    const int ln   = lane & 15;      // MFMA col (chunk) index
    const int lq   = lane >> 4;      // quad 0..3

    __shared__ __align__(16) __half h_sh[16][HPAD];   // rows 0..3 = chunks, rest zero
    __shared__ __align__(16) float red[4][772];       // gates [chunk][768]

    // W fragments: 3 tiles x 8 k-chunks, resident (96 VGPRs/AGPRs)
    f16x8 Wf[3][8];
#pragma unroll
    for (int tt = 0; tt < 3; ++tt)
#pragma unroll
        for (int c = 0; c < 8; ++c)
            Wf[tt][c] = Wk[(size_t)((3 * wv + tt) * 8 + c) * 64 + lane];

    for (int idx = tid; idx < 16 * HPAD; idx += 1024) ((__half*)h_sh)[idx] = __float2half(0.f);

    const int i   = tid & 255;
    const int grp = tid >> 8;        // chunk 0..3
    const float bn_ = bh[512 + i];   // b_hh n-gate (r,z folded into gx)
    float h_own = 0.f;
    const int cbase = blockIdx.x * BQ;
    const int dtv = dir ? -1 : 1;
    const int lo = (cbase + grp) * CHUNK;
    const int t0 = dir ? (lo + CHUNK - 1 + WARM) : (lo - WARM);
    __syncthreads();

    for (int s = 0; s < GSTEPS; ++s) {
        const int t = t0 + dtv * s;
        const bool valid = ((unsigned)t < (unsigned)T_LEN);
        const int tc2 = t < 0 ? 0 : (t > T_LEN - 1 ? T_LEN - 1 : t);
        const float* g = gx + (size_t)tc2 * G3 + i;
        const float xr = g[0], xz = g[256], xn = g[512];

        f32x4 acc[3];
#pragma unroll
        for (int tt = 0; tt < 3; ++tt) acc[tt] = (f32x4)0.f;
#pragma unroll
        for (int c = 0; c < 8; ++c) {
            f16x8 bfr = *(const f16x8*)&h_sh[ln][c * 32 + lq * 8];
#pragma unroll
            for (int tt = 0; tt < 3; ++tt)
                acc[tt] = __builtin_amdgcn_mfma_f32_16x16x32_f16(Wf[tt][c], bfr, acc[tt], 0, 0, 0);
        }
        if (ln < 4) {
#pragma unroll
            for (int tt = 0; tt < 3; ++tt)
                *(f32x4*)&red[ln][(3 * wv + tt) * 16 + lq * 4] = acc[tt];
        }
        __syncthreads();   // gates visible; h reads done

        const float r = fsig(xr + red[grp][i]);
        const float z = fsig(xz + red[grp][256 + i]);
        const float nn = ftanh(xn + r * (red[grp][512 + i] + bn_));
        const float hnew = (1.f - z) * nn + z * h_own;
        if (valid) {
            h_own = hnew;
            h_sh[grp][i] = __float2half(hnew);
            const bool pay = dir ? (t < lo + CHUNK) : (t >= lo);
            if (pay) Hbuf[(size_t)t * 512 + col_off + i] = hnew;
        }
        __syncthreads();   // new h visible before next step's B-frag reads
    }
}

// ---------------- select: top-8 + softmax weights (register-resident scan) ----------------
__global__ __launch_bounds__(256) void select_topk_kernel(
    const float* __restrict__ scores, const float* __restrict__ temp_p,
    int* __restrict__ sel_idx_out, float* __restrict__ sel_w_out) {
    __shared__ float red_v[4];
    __shared__ int   red_i[4];
    __shared__ int   bcast_idx;
    __shared__ int   sel_idx_sh[NFRM];
    __shared__ float sel_v_sh[NFRM];

    const int tid  = threadIdx.x;
    const int lane = tid & 63;
    const int wv   = tid >> 6;

    float sv[64];
#pragma unroll
    for (int a = 0; a < 64; ++a) sv[a] = scores[a * 256 + tid];

    for (int round = 0; round < NFRM; ++round) {
        float best = -1e30f;
        int bidx = 0x7fffffff;
#pragma unroll
        for (int a = 0; a < 64; ++a) {
            if (sv[a] > best) { best = sv[a]; bidx = a * 256 + tid; }
        }
#pragma unroll
        for (int off = 32; off > 0; off >>= 1) {
            float v2 = __shfl_down(best, off);
            int   i2 = __shfl_down(bidx, off);
            if (v2 > best || (v2 == best && i2 < bidx)) { best = v2; bidx = i2; }
        }
        if (lane == 0) { red_v[wv] = best; red_i[wv] = bidx; }
        __syncthreads();
        if (tid == 0) {
            float bv = red_v[0]; int bi = red_i[0];
#pragma unroll
            for (int w = 1; w < 4; ++w)
                if (red_v[w] > bv || (red_v[w] == bv && red_i[w] < bi)) { bv = red_v[w]; bi = red_i[w]; }
            sel_idx_sh[round] = bi; sel_v_sh[round] = bv; bcast_idx = bi;
        }
        __syncthreads();
        const int widx = bcast_idx;
        if ((widx & 255) == tid) {
            const int aa = widx >> 8;
#pragma unroll
            for (int a = 0; a < 64; ++a)
                if (a == aa) sv[a] = -1e30f;
        }
    }

    if (tid == 0) {
        float temp = temp_p[0];
        float m = sel_v_sh[0];
        float e[NFRM];
        float sum = 0.f;
        for (int j = 0; j < NFRM; ++j) { e[j] = expf((sel_v_sh[j] - m) / temp); sum += e[j]; }
        for (int j = 0; j < NFRM; ++j) { sel_idx_out[j] = sel_idx_sh[j]; sel_w_out[j] = e[j] / sum; }
    }
}

// ---------------- classifier layer 1: 256 blocks, one hidden row each ----------------
__global__ __launch_bounds__(256) void classifier1_kernel(
    const float* __restrict__ features,
    const int* __restrict__ sel_idx, const float* __restrict__ sel_w,
    const float* __restrict__ Wc1, const float* __restrict__ bc1,
    float* __restrict__ hid) {
    const int r = blockIdx.x;
    const int tid = threadIdx.x;
    __shared__ int   s_idx[NFRM];
    __shared__ float s_w[NFRM];
    __shared__ float part[4];
    if (tid < NFRM) { s_idx[tid] = sel_idx[tid]; s_w[tid] = sel_w[tid]; }
    __syncthreads();

    float acc = 0.f;
#pragma unroll
    for (int q = 0; q < D_IN / 256; ++q) {
        int d = q * 256 + tid;
        float c = 0.f;
#pragma unroll
        for (int j = 0; j < NFRM; ++j)
            c += s_w[j] * features[(size_t)s_idx[j] * D_IN + d];
        acc += c * Wc1[(size_t)r * D_IN + d];
    }
#pragma unroll
    for (int off = 32; off > 0; off >>= 1) acc += __shfl_down(acc, off);
    if ((tid & 63) == 0) part[tid >> 6] = acc;
    __syncthreads();
    if (tid == 0)
        hid[r] = fmaxf(part[0] + part[1] + part[2] + part[3] + bc1[r], 0.f);
}

// ---------------- classifier layer 2: logits ----------------
__global__ __launch_bounds__(128) void classifier2_kernel(
    const float* __restrict__ hid, const float* __restrict__ Wc2,
    const float* __restrict__ bc2, float* __restrict__ out) {
    const int tid = threadIdx.x;
    const int c = tid >> 6;
    const int l = tid & 63;
    float acc = 0.f;
#pragma unroll
    for (int k = l; k < 256; k += 64) acc += hid[k] * Wc2[c * 256 + k];
#pragma unroll
    for (int off = 32; off > 0; off >>= 1) acc += __shfl_down(acc, off);
    if (l == 0) out[c] = acc + bc2[c];
}

// ---------------- launcher ----------------
extern "C" void kernel_launch(void* const* d_in, const int* in_sizes, int n_in,
                              void* d_out, int out_size, void* d_ws, size_t ws_size,
                              hipStream_t stream) {
    const float* features = (const float*)d_in[0];
    const float* temperature = (const float*)d_in[1];
    const float* W_ih_f = (const float*)d_in[2];
    const float* W_hh_f = (const float*)d_in[3];
    const float* b_ih_f = (const float*)d_in[4];
    const float* b_hh_f = (const float*)d_in[5];
    const float* W_ih_b = (const float*)d_in[6];
    const float* W_hh_b = (const float*)d_in[7];
    const float* b_ih_b = (const float*)d_in[8];
    const float* b_hh_b = (const float*)d_in[9];
    const float* Ws1 = (const float*)d_in[10];
    const float* bs1 = (const float*)d_in[11];
    const float* Ws2 = (const float*)d_in[12];
    const float* bs2 = (const float*)d_in[13];
    const float* Wc1 = (const float*)d_in[14];
    const float* bc1 = (const float*)d_in[15];
    const float* Wc2 = (const float*)d_in[16];
    const float* bc2 = (const float*)d_in[17];

    float* ws = (float*)d_ws;
    float* gx_f = ws + OFF_GXF;
    float* gx_b = ws + OFF_GXB;
    float* Hbuf = ws + OFF_H;
    float* biaf = ws + OFF_BIA;
    float* biab = ws + OFF_BIA + G3;
    float* sc   = ws + OFF_SC;
    f16x8* Wk_f = (f16x8*)(ws + OFF_WPF);
    f16x8* Wk_b = (f16x8*)(ws + OFF_WPB);
    int*   sel_i = (int*)(ws + OFF_SEL);
    float* sel_w = ws + OFF_SEL + NFRM;
    float* chid  = ws + OFF_CH;
    float* out  = (float*)d_out;

    // B16 borrows the Hbuf region (dead until the GRU runs)
    __half* B16 = (__half*)(ws + OFF_H);

    // fold b_hh(r,z) into input-projection bias
    bias_fold_kernel<<<3, 256, 0, stream>>>(b_ih_f, b_hh_f, b_ih_b, b_hh_b, biaf, biab);

    // convert input-projection weights to fp16 (both dirs concatenated)
    cvt_w_kernel<<<dim3(768, 2), 256, 0, stream>>>(W_ih_f, W_ih_b, B16);

    // pack recurrent weights into MFMA fragment order
    pack_whh_mfma_kernel<<<dim3(384, 2), 64, 0, stream>>>(W_hh_f, W_hh_b, Wk_f, Wk_b);

    // gx_{f,b} = features @ W_ih^T + (b_ih + b_hh[r,z])  (direct-reg MFMA GEMM)
    gemm_gx_kernel<<<1536, 256, 0, stream>>>(features, B16, biaf, biab, gx_f, gx_b);

    // chunked BiGRU v5 (W-resident MFMA, 1024-thread blocks)
    gru_v5_kernel<<<dim3(GRU_BLOCKS, 2), 1024, 0, stream>>>(
        gx_f, gx_b, Wk_f, Wk_b, b_hh_f, b_hh_b, Hbuf);

    // fused scorer (layer1 GEMM + layer2 dot) -> scores
    scorer_kernel<<<T_LEN / BM, 256, 0, stream>>>(
        Hbuf, Ws1, bs1, Ws2, bs2, sc, out + 2, T_LEN, 64, 512);

    // top-8 + softmax weights
    select_topk_kernel<<<1, 256, 0, stream>>>(sc, temperature, sel_i, sel_w);

    // classifier layer 1 (parallel over rows, clip computed on the fly)
    classifier1_kernel<<<256, 256, 0, stream>>>(features, sel_i, sel_w, Wc1, bc1, chid);

    // classifier layer 2 -> logits
    classifier2_kernel<<<1, 128, 0, stream>>>(chid, Wc2, bc2, out);
}

// Round 5
// 678.650 us; speedup vs baseline: 1.4416x; 1.4416x over previous
//
#include <hip/hip_runtime.h>
#include <hip/hip_fp16.h>
#include <math.h>

// ---------------- problem constants ----------------
#define T_LEN 16384
#define D_IN  2048
#define H_GRU 256
#define G3    768      // 3*H
#define NFRM  8
#define NCLS  2

// GRU chunking: CHUNK=32 payload, WARM=48 warmup, BQ=4 chunks/block.
#define CHUNK 32
#define WARM  48
#define GSTEPS (WARM + CHUNK)           // 80
#define BQ    4
#define NCHUNK (T_LEN / CHUNK)          // 512 per dir
#define GRU_BLOCKS (NCHUNK / BQ)        // 128 per dir

typedef _Float16 f16x8 __attribute__((ext_vector_type(8)));
typedef float    f32x4 __attribute__((ext_vector_type(4)));

// ---------------- workspace layout (in floats) ----------------
static const size_t OFF_GXF = 0;
static const size_t OFF_GXB = OFF_GXF + (size_t)T_LEN * G3;
static const size_t OFF_H   = OFF_GXB + (size_t)T_LEN * G3;
static const size_t OFF_BIA = OFF_H   + (size_t)T_LEN * 512;    // folded biases 2*768
static const size_t OFF_SC  = OFF_BIA + 2 * G3;
static const size_t OFF_WPF = OFF_SC  + (size_t)T_LEN;          // f16x8[48*8*64] = 393216 B
static const size_t OFF_WPB = OFF_WPF + (size_t)G3 * H_GRU / 2;
static const size_t OFF_SEL = OFF_WPB + (size_t)G3 * H_GRU / 2; // 8 int idx + 8 float w
static const size_t OFF_CH  = OFF_SEL + 16;                     // 256 floats hidden
// total ~134 MB
// NOTE: B16 (fp16 W_ih_cat, 1536x2048 = 6.3 MB) lives in the Hbuf region
// (ws + OFF_H) during the GEMM; Hbuf is only written by the GRU afterwards.

__device__ __forceinline__ float fsig(float x) {
    return __builtin_amdgcn_rcpf(1.f + __expf(-x));
}
__device__ __forceinline__ float ftanh(float x) {
    float e = __expf(2.f * x);
    return 1.f - 2.f * __builtin_amdgcn_rcpf(e + 1.f);
}

__device__ __forceinline__ f16x8 pack8(const f32x4 lo, const f32x4 hi) {
    f16x8 r;
    r[0] = (_Float16)lo[0]; r[1] = (_Float16)lo[1];
    r[2] = (_Float16)lo[2]; r[3] = (_Float16)lo[3];
    r[4] = (_Float16)hi[0]; r[5] = (_Float16)hi[1];
    r[6] = (_Float16)hi[2]; r[7] = (_Float16)hi[3];
    return r;
}

// ---------------- fold b_hh (r,z gates) into the input-projection bias ----------------
__global__ void bias_fold_kernel(const float* __restrict__ bi0, const float* __restrict__ bh0,
                                 const float* __restrict__ bi1, const float* __restrict__ bh1,
                                 float* __restrict__ o0, float* __restrict__ o1) {
    int t = blockIdx.x * 256 + threadIdx.x;
    if (t < G3) {
        float a0 = bi0[t], a1 = bi1[t];
        if (t < 512) { a0 += bh0[t]; a1 += bh1[t]; }
        o0[t] = a0; o1[t] = a1;
    }
}

// ---------------- convert W_ih_{f,b} (fp32) -> B16 fp16 [1536][2048] ----------------
__global__ __launch_bounds__(256) void cvt_w_kernel(const float* __restrict__ Wf,
                                                    const float* __restrict__ Wb,
                                                    __half* __restrict__ B16) {
    const float* __restrict__ src = blockIdx.y ? Wb : Wf;
    __half* __restrict__ dst = B16 + (size_t)blockIdx.y * G3 * D_IN;
    const int i = blockIdx.x * 256 + threadIdx.x;    // 8 floats per thread
    float4 a = *(const float4*)&src[(size_t)i * 8];
    float4 b = *(const float4*)&src[(size_t)i * 8 + 4];
    __half2 h[4];
    h[0] = __float22half2_rn(make_float2(a.x, a.y));
    h[1] = __float22half2_rn(make_float2(a.z, a.w));
    h[2] = __float22half2_rn(make_float2(b.x, b.y));
    h[3] = __float22half2_rn(make_float2(b.z, b.w));
    *(float4*)&dst[(size_t)i * 8] = *(float4*)h;
}

// ---------------- pack W_hh into MFMA A-fragment order ----------------
__global__ void pack_whh_mfma_kernel(const float* __restrict__ W0,
                                     const float* __restrict__ W1,
                                     f16x8* __restrict__ P0,
                                     f16x8* __restrict__ P1) {
    const float* W = blockIdx.y ? W1 : W0;
    f16x8* P = blockIdx.y ? P1 : P0;
    int tc = blockIdx.x;             // 0..383 = t*8 + c
    int l = threadIdx.x;             // 0..63
    int t = tc >> 3, c = tc & 7;
    int m = t * 16 + (l & 15);
    int k = c * 32 + (l >> 4) * 8;
    const float* src = W + (size_t)m * H_GRU + k;
    f16x8 v;
#pragma unroll
    for (int j = 0; j < 8; ++j) v[j] = (_Float16)src[j];
    P[(size_t)tc * 64 + l] = v;
}

// ---------------- gx GEMM: R0 structure + fragment-order LDS + fp16 B ----------------
// C[M][768] per dir = A[M][2048](f32) @ B16^T + bias. 128x128 tile, BK=32,
// 4 waves, reg-staged LDS (the proven-fastest structure: compiler pipelines
// the global loads across the 2-barrier loop; ~3 blocks/CU TLP hides latency).
// Deltas vs the 220us baseline: (1) fragment-order LDS -> both ds_write_b128
// and ds_read_b128 are lane-contiguous (kills the 1.26e7 8-way read
// conflicts); (2) B pre-converted fp16 -> one f16x8 load, no in-loop cvt.
// No XCD swizzle: x-fastest dispatch keeps one B-panel L2-resident per XCD;
// A re-reads are L3-served (A=134MB < 256MB L3).
#define GM 128
#define GN 128
#define GK 32
__global__ __launch_bounds__(256, 2) void gemm_f16_kernel(
    const float* __restrict__ A,      // features [16384][2048] f32
    const __half* __restrict__ B16,   // [1536][2048] f16 (dir-concat)
    const float* __restrict__ biaf, const float* __restrict__ biab,
    float* __restrict__ Cf, float* __restrict__ Cb) {
    // fragment-order LDS: frag f = 0..7 covers rows [16f,16f+16);
    // lane l of frag -> row 16f+(l&15), k ((l>>4)&3)*8; 1KB per frag.
    __shared__ __align__(16) __half As[4096];   // 8 KB
    __shared__ __align__(16) __half Bs[4096];   // 8 KB

    const int tid  = threadIdx.x;
    const int lane = tid & 63;
    const int wave = tid >> 6;
    const int lm   = lane & 15;
    const int lk   = lane >> 4;
    const int mw   = wave & 1;
    const int nw   = wave >> 1;

    const int bm  = blockIdx.x * GM;
    const int nt  = blockIdx.y;             // 0..5
    const int dir = blockIdx.z;
    const int bnt = dir * G3 + nt * GN;     // row offset into B16 [0..1535]
    const int bn_local = nt * GN;
    const float* __restrict__ bias = dir ? biab : biaf;
    float* __restrict__ C          = dir ? Cb  : Cf;

    // staging: thread covers rows (arow, arow+64) at k-offset acol (8 elems);
    // its LDS slot = frag (tid>>6) [+4 for the second row], lane (tid&63).
    const int arow = ((tid >> 6) << 4) + (tid & 15);     // 0..63
    const int acol = ((tid >> 4) & 3) * 8;
    const int slot = (tid >> 6) * 512 + (tid & 63) * 8;  // halfs
    const float*  gA = A   + (size_t)(bm  + arow) * D_IN + acol;
    const __half* gB = B16 + (size_t)(bnt + arow) * D_IN + acol;

    f32x4 acc[4][4];
#pragma unroll
    for (int a = 0; a < 4; ++a)
#pragma unroll
        for (int b = 0; b < 4; ++b) acc[a][b] = (f32x4)0.f;

    for (int k0 = 0; k0 < D_IN; k0 += GK) {
        // global loads for this tile (compiler hoists next-iter copies into
        // the MFMA region; do not pin with unroll/sched pragmas)
        f32x4 a0 = *(const f32x4*)(gA + k0);
        f32x4 a1 = *(const f32x4*)(gA + k0 + 4);
        f32x4 a2 = *(const f32x4*)(gA + (size_t)64 * D_IN + k0);
        f32x4 a3 = *(const f32x4*)(gA + (size_t)64 * D_IN + k0 + 4);
        f16x8 b0 = *(const f16x8*)(gB + k0);
        f16x8 b1 = *(const f16x8*)(gB + (size_t)64 * D_IN + k0);
        __syncthreads();   // previous tile's reads done
        *(f16x8*)&As[slot]        = pack8(a0, a1);
        *(f16x8*)&As[slot + 2048] = pack8(a2, a3);
        *(f16x8*)&Bs[slot]        = b0;
        *(f16x8*)&Bs[slot + 2048] = b1;
        __syncthreads();   // tile resident

        f16x8 afr[4], bfr[4];
#pragma unroll
        for (int tm = 0; tm < 4; ++tm)
            afr[tm] = *(const f16x8*)&As[(4 * mw + tm) * 512 + lane * 8];
#pragma unroll
        for (int tn = 0; tn < 4; ++tn)
            bfr[tn] = *(const f16x8*)&Bs[(4 * nw + tn) * 512 + lane * 8];
#pragma unroll
        for (int tm = 0; tm < 4; ++tm)
#pragma unroll
            for (int tn = 0; tn < 4; ++tn)
                acc[tm][tn] = __builtin_amdgcn_mfma_f32_16x16x32_f16(
                    afr[tm], bfr[tn], acc[tm][tn], 0, 0, 0);
    }

#pragma unroll
    for (int tm = 0; tm < 4; ++tm) {
#pragma unroll
        for (int tn = 0; tn < 4; ++tn) {
            int gn = bn_local + 64 * nw + 16 * tn + lm;
            float bb = bias[gn];
#pragma unroll
            for (int reg = 0; reg < 4; ++reg) {
                int gm = bm + 64 * mw + 16 * tm + lk * 4 + reg;
                C[(size_t)gm * G3 + gn] = acc[tm][tn][reg] + bb;
            }
        }
    }
}

// ---------------- scorer: scores = relu(Hbuf @ Ws1^T + bs1) @ Ws2^T + bs2 ----------------
// 64x64 tile over M, N=64 fixed (whole Ws1), layer-2 dot fused in epilogue.
#define BM 64
#define BN 64
#define BK 32
__global__ __launch_bounds__(256) void scorer_kernel(
    const float* __restrict__ A,       // Hbuf [T][512]
    const float* __restrict__ B,       // Ws1 [64][512]
    const float* __restrict__ bias,    // bs1 [64]
    const float* __restrict__ Ws2,     // [64]
    const float* __restrict__ bs2,     // [1]
    float* __restrict__ sc, float* __restrict__ outs,
    int M, int N, int K) {
    __shared__ __align__(16) float As[BK][BM + 4];
    __shared__ __align__(16) float Bs[BK][BN + 4];

    const int tid = threadIdx.x;
    const int bm = blockIdx.x * BM;
    const int kk8 = tid & 7;
    const int r32 = tid >> 3;
    const int tx = tid & 15;
    const int ty = tid >> 4;

    float acc[4][4];
#pragma unroll
    for (int a = 0; a < 4; ++a)
#pragma unroll
        for (int b = 0; b < 4; ++b) acc[a][b] = 0.f;

    for (int k0 = 0; k0 < K; k0 += BK) {
        float4 a0 = *(const float4*)&A[(size_t)(bm + r32) * K + k0 + kk8 * 4];
        float4 a1 = *(const float4*)&A[(size_t)(bm + r32 + 32) * K + k0 + kk8 * 4];
        float4 b0 = *(const float4*)&B[(size_t)(r32) * K + k0 + kk8 * 4];
        float4 b1 = *(const float4*)&B[(size_t)(r32 + 32) * K + k0 + kk8 * 4];
        __syncthreads();
        As[kk8 * 4 + 0][r32] = a0.x; As[kk8 * 4 + 1][r32] = a0.y;
        As[kk8 * 4 + 2][r32] = a0.z; As[kk8 * 4 + 3][r32] = a0.w;
        As[kk8 * 4 + 0][r32 + 32] = a1.x; As[kk8 * 4 + 1][r32 + 32] = a1.y;
        As[kk8 * 4 + 2][r32 + 32] = a1.z; As[kk8 * 4 + 3][r32 + 32] = a1.w;
        Bs[kk8 * 4 + 0][r32] = b0.x; Bs[kk8 * 4 + 1][r32] = b0.y;
        Bs[kk8 * 4 + 2][r32] = b0.z; Bs[kk8 * 4 + 3][r32] = b0.w;
        Bs[kk8 * 4 + 0][r32 + 32] = b1.x; Bs[kk8 * 4 + 1][r32 + 32] = b1.y;
        Bs[kk8 * 4 + 2][r32 + 32] = b1.z; Bs[kk8 * 4 + 3][r32 + 32] = b1.w;
        __syncthreads();
#pragma unroll 8
        for (int kk = 0; kk < BK; ++kk) {
            float4 av = *(const float4*)&As[kk][ty * 4];
            float4 bv = *(const float4*)&Bs[kk][tx * 4];
            acc[0][0] += av.x * bv.x; acc[0][1] += av.x * bv.y; acc[0][2] += av.x * bv.z; acc[0][3] += av.x * bv.w;
            acc[1][0] += av.y * bv.x; acc[1][1] += av.y * bv.y; acc[1][2] += av.y * bv.z; acc[1][3] += av.y * bv.w;
            acc[2][0] += av.z * bv.x; acc[2][1] += av.z * bv.y; acc[2][2] += av.z * bv.z; acc[2][3] += av.z * bv.w;
            acc[3][0] += av.w * bv.x; acc[3][1] += av.w * bv.y; acc[3][2] += av.w * bv.z; acc[3][3] += av.w * bv.w;
        }
    }

    // fused layer 2: per-thread partial dot over its 4 cols, reduce across tx group
    float4 bvv = *(const float4*)&bias[tx * 4];
    float4 w2  = *(const float4*)&Ws2[tx * 4];
    const float b2 = bs2[0];
#pragma unroll
    for (int im = 0; im < 4; ++im) {
        float s = fmaxf(acc[im][0] + bvv.x, 0.f) * w2.x
                + fmaxf(acc[im][1] + bvv.y, 0.f) * w2.y
                + fmaxf(acc[im][2] + bvv.z, 0.f) * w2.z
                + fmaxf(acc[im][3] + bvv.w, 0.f) * w2.w;
#pragma unroll
        for (int off = 1; off < 16; off <<= 1) s += __shfl_xor(s, off);
        if (tx == 0) {
            int m = bm + ty * 4 + im;
            float sval = s + b2;
            sc[m] = sval;
            outs[m] = sval;
        }
    }
}

// ---------------- chunked BiGRU v5: W-resident MFMA, 1024-thread blocks ----------------
// 16 waves, wave wv owns 3 row-tiles (48 gate rows) of W in registers (96 VGPRs).
// Epilogue: thread (grp=tid>>8, i=tid&255) owns chunk grp, row i (1 state/thread).
#define HPAD 272
__global__ __launch_bounds__(1024, 4) void gru_v5_kernel(
    const float* __restrict__ gx0, const float* __restrict__ gx1,
    const f16x8* __restrict__ Wk0, const f16x8* __restrict__ Wk1,
    const float* __restrict__ bh0, const float* __restrict__ bh1,
    float* __restrict__ Hbuf) {
    const int dir = blockIdx.y;
    const float* __restrict__ gx = dir ? gx1 : gx0;
    const f16x8* __restrict__ Wk = dir ? Wk1 : Wk0;
    const float* __restrict__ bh = dir ? bh1 : bh0;
    const int col_off = dir * 256;

    const int tid  = threadIdx.x;
    const int lane = tid & 63;
    const int wv   = tid >> 6;       // wave 0..15
    const int ln   = lane & 15;      // MFMA col (chunk) index
    const int lq   = lane >> 4;      // quad 0..3

    __shared__ __align__(16) __half h_sh[16][HPAD];   // rows 0..3 = chunks, rest zero
    __shared__ __align__(16) float red[4][772];       // gates [chunk][768]

    // W fragments: 3 tiles x 8 k-chunks, resident (96 VGPRs/AGPRs)
    f16x8 Wf[3][8];
#pragma unroll
    for (int tt = 0; tt < 3; ++tt)
#pragma unroll
        for (int c = 0; c < 8; ++c)
            Wf[tt][c] = Wk[(size_t)((3 * wv + tt) * 8 + c) * 64 + lane];

    for (int idx = tid; idx < 16 * HPAD; idx += 1024) ((__half*)h_sh)[idx] = __float2half(0.f);

    const int i   = tid & 255;
    const int grp = tid >> 8;        // chunk 0..3
    const float bn_ = bh[512 + i];   // b_hh n-gate (r,z folded into gx)
    float h_own = 0.f;
    const int cbase = blockIdx.x * BQ;
    const int dtv = dir ? -1 : 1;
    const int lo = (cbase + grp) * CHUNK;
    const int t0 = dir ? (lo + CHUNK - 1 + WARM) : (lo - WARM);
    __syncthreads();

    for (int s = 0; s < GSTEPS; ++s) {
        const int t = t0 + dtv * s;
        const bool valid = ((unsigned)t < (unsigned)T_LEN);
        const int tc2 = t < 0 ? 0 : (t > T_LEN - 1 ? T_LEN - 1 : t);
        const float* g = gx + (size_t)tc2 * G3 + i;
        const float xr = g[0], xz = g[256], xn = g[512];

        f32x4 acc[3];
#pragma unroll
        for (int tt = 0; tt < 3; ++tt) acc[tt] = (f32x4)0.f;
#pragma unroll
        for (int c = 0; c < 8; ++c) {
            f16x8 bfr = *(const f16x8*)&h_sh[ln][c * 32 + lq * 8];
#pragma unroll
            for (int tt = 0; tt < 3; ++tt)
                acc[tt] = __builtin_amdgcn_mfma_f32_16x16x32_f16(Wf[tt][c], bfr, acc[tt], 0, 0, 0);
        }
        if (ln < 4) {
#pragma unroll
            for (int tt = 0; tt < 3; ++tt)
                *(f32x4*)&red[ln][(3 * wv + tt) * 16 + lq * 4] = acc[tt];
        }
        __syncthreads();   // gates visible; h reads done

        const float r = fsig(xr + red[grp][i]);
        const float z = fsig(xz + red[grp][256 + i]);
        const float nn = ftanh(xn + r * (red[grp][512 + i] + bn_));
        const float hnew = (1.f - z) * nn + z * h_own;
        if (valid) {
            h_own = hnew;
            h_sh[grp][i] = __float2half(hnew);
            const bool pay = dir ? (t < lo + CHUNK) : (t >= lo);
            if (pay) Hbuf[(size_t)t * 512 + col_off + i] = hnew;
        }
        __syncthreads();   // new h visible before next step's B-frag reads
    }
}

// ---------------- select: top-8 + softmax weights (register-resident scan) ----------------
__global__ __launch_bounds__(256) void select_topk_kernel(
    const float* __restrict__ scores, const float* __restrict__ temp_p,
    int* __restrict__ sel_idx_out, float* __restrict__ sel_w_out) {
    __shared__ float red_v[4];
    __shared__ int   red_i[4];
    __shared__ int   bcast_idx;
    __shared__ int   sel_idx_sh[NFRM];
    __shared__ float sel_v_sh[NFRM];

    const int tid  = threadIdx.x;
    const int lane = tid & 63;
    const int wv   = tid >> 6;

    float sv[64];
#pragma unroll
    for (int a = 0; a < 64; ++a) sv[a] = scores[a * 256 + tid];

    for (int round = 0; round < NFRM; ++round) {
        float best = -1e30f;
        int bidx = 0x7fffffff;
#pragma unroll
        for (int a = 0; a < 64; ++a) {
            if (sv[a] > best) { best = sv[a]; bidx = a * 256 + tid; }
        }
#pragma unroll
        for (int off = 32; off > 0; off >>= 1) {
            float v2 = __shfl_down(best, off);
            int   i2 = __shfl_down(bidx, off);
            if (v2 > best || (v2 == best && i2 < bidx)) { best = v2; bidx = i2; }
        }
        if (lane == 0) { red_v[wv] = best; red_i[wv] = bidx; }
        __syncthreads();
        if (tid == 0) {
            float bv = red_v[0]; int bi = red_i[0];
#pragma unroll
            for (int w = 1; w < 4; ++w)
                if (red_v[w] > bv || (red_v[w] == bv && red_i[w] < bi)) { bv = red_v[w]; bi = red_i[w]; }
            sel_idx_sh[round] = bi; sel_v_sh[round] = bv; bcast_idx = bi;
        }
        __syncthreads();
        const int widx = bcast_idx;
        if ((widx & 255) == tid) {
            const int aa = widx >> 8;
#pragma unroll
            for (int a = 0; a < 64; ++a)
                if (a == aa) sv[a] = -1e30f;
        }
    }

    if (tid == 0) {
        float temp = temp_p[0];
        float m = sel_v_sh[0];
        float e[NFRM];
        float sum = 0.f;
        for (int j = 0; j < NFRM; ++j) { e[j] = expf((sel_v_sh[j] - m) / temp); sum += e[j]; }
        for (int j = 0; j < NFRM; ++j) { sel_idx_out[j] = sel_idx_sh[j]; sel_w_out[j] = e[j] / sum; }
    }
}

// ---------------- classifier layer 1: 256 blocks, one hidden row each ----------------
__global__ __launch_bounds__(256) void classifier1_kernel(
    const float* __restrict__ features,
    const int* __restrict__ sel_idx, const float* __restrict__ sel_w,
    const float* __restrict__ Wc1, const float* __restrict__ bc1,
    float* __restrict__ hid) {
    const int r = blockIdx.x;
    const int tid = threadIdx.x;
    __shared__ int   s_idx[NFRM];
    __shared__ float s_w[NFRM];
    __shared__ float part[4];
    if (tid < NFRM) { s_idx[tid] = sel_idx[tid]; s_w[tid] = sel_w[tid]; }
    __syncthreads();

    float acc = 0.f;
#pragma unroll
    for (int q = 0; q < D_IN / 256; ++q) {
        int d = q * 256 + tid;
        float c = 0.f;
#pragma unroll
        for (int j = 0; j < NFRM; ++j)
            c += s_w[j] * features[(size_t)s_idx[j] * D_IN + d];
        acc += c * Wc1[(size_t)r * D_IN + d];
    }
#pragma unroll
    for (int off = 32; off > 0; off >>= 1) acc += __shfl_down(acc, off);
    if ((tid & 63) == 0) part[tid >> 6] = acc;
    __syncthreads();
    if (tid == 0)
        hid[r] = fmaxf(part[0] + part[1] + part[2] + part[3] + bc1[r], 0.f);
}

// ---------------- classifier layer 2: logits ----------------
__global__ __launch_bounds__(128) void classifier2_kernel(
    const float* __restrict__ hid, const float* __restrict__ Wc2,
    const float* __restrict__ bc2, float* __restrict__ out) {
    const int tid = threadIdx.x;
    const int c = tid >> 6;
    const int l = tid & 63;
    float acc = 0.f;
#pragma unroll
    for (int k = l; k < 256; k += 64) acc += hid[k] * Wc2[c * 256 + k];
#pragma unroll
    for (int off = 32; off > 0; off >>= 1) acc += __shfl_down(acc, off);
    if (l == 0) out[c] = acc + bc2[c];
}

// ---------------- launcher ----------------
extern "C" void kernel_launch(void* const* d_in, const int* in_sizes, int n_in,
                              void* d_out, int out_size, void* d_ws, size_t ws_size,
                              hipStream_t stream) {
    const float* features = (const float*)d_in[0];
    const float* temperature = (const float*)d_in[1];
    const float* W_ih_f = (const float*)d_in[2];
    const float* W_hh_f = (const float*)d_in[3];
    const float* b_ih_f = (const float*)d_in[4];
    const float* b_hh_f = (const float*)d_in[5];
    const float* W_ih_b = (const float*)d_in[6];
    const float* W_hh_b = (const float*)d_in[7];
    const float* b_ih_b = (const float*)d_in[8];
    const float* b_hh_b = (const float*)d_in[9];
    const float* Ws1 = (const float*)d_in[10];
    const float* bs1 = (const float*)d_in[11];
    const float* Ws2 = (const float*)d_in[12];
    const float* bs2 = (const float*)d_in[13];
    const float* Wc1 = (const float*)d_in[14];
    const float* bc1 = (const float*)d_in[15];
    const float* Wc2 = (const float*)d_in[16];
    const float* bc2 = (const float*)d_in[17];

    float* ws = (float*)d_ws;
    float* gx_f = ws + OFF_GXF;
    float* gx_b = ws + OFF_GXB;
    float* Hbuf = ws + OFF_H;
    float* biaf = ws + OFF_BIA;
    float* biab = ws + OFF_BIA + G3;
    float* sc   = ws + OFF_SC;
    f16x8* Wk_f = (f16x8*)(ws + OFF_WPF);
    f16x8* Wk_b = (f16x8*)(ws + OFF_WPB);
    int*   sel_i = (int*)(ws + OFF_SEL);
    float* sel_w = ws + OFF_SEL + NFRM;
    float* chid  = ws + OFF_CH;
    float* out  = (float*)d_out;

    // B16 borrows the Hbuf region (dead until the GRU runs)
    __half* B16 = (__half*)(ws + OFF_H);

    // fold b_hh(r,z) into input-projection bias
    bias_fold_kernel<<<3, 256, 0, stream>>>(b_ih_f, b_hh_f, b_ih_b, b_hh_b, biaf, biab);

    // convert input-projection weights to fp16 (both dirs concatenated)
    cvt_w_kernel<<<dim3(768, 2), 256, 0, stream>>>(W_ih_f, W_ih_b, B16);

    // pack recurrent weights into MFMA fragment order
    pack_whh_mfma_kernel<<<dim3(384, 2), 64, 0, stream>>>(W_hh_f, W_hh_b, Wk_f, Wk_b);

    // gx_{f,b} = features @ W_ih^T + (b_ih + b_hh[r,z])  (R0 structure, frag-order LDS)
    gemm_f16_kernel<<<dim3(T_LEN / GM, G3 / GN, 2), 256, 0, stream>>>(
        features, B16, biaf, biab, gx_f, gx_b);

    // chunked BiGRU v5 (W-resident MFMA, 1024-thread blocks)
    gru_v5_kernel<<<dim3(GRU_BLOCKS, 2), 1024, 0, stream>>>(
        gx_f, gx_b, Wk_f, Wk_b, b_hh_f, b_hh_b, Hbuf);

    // fused scorer (layer1 GEMM + layer2 dot) -> scores
    scorer_kernel<<<T_LEN / BM, 256, 0, stream>>>(
        Hbuf, Ws1, bs1, Ws2, bs2, sc, out + 2, T_LEN, 64, 512);

    // top-8 + softmax weights
    select_topk_kernel<<<1, 256, 0, stream>>>(sc, temperature, sel_i, sel_w);

    // classifier layer 1 (parallel over rows, clip computed on the fly)
    classifier1_kernel<<<256, 256, 0, stream>>>(features, sel_i, sel_w, Wc1, bc1, chid);

    // classifier layer 2 -> logits
    classifier2_kernel<<<1, 128, 0, stream>>>(chid, Wc2, bc2, out);
}

// Round 6
// 593.403 us; speedup vs baseline: 1.6487x; 1.1437x over previous
//
#include <hip/hip_runtime.h>
#include <hip/hip_fp16.h>
#include <math.h>

// ---------------- problem constants ----------------
#define T_LEN 16384
#define D_IN  2048
#define H_GRU 256
#define G3    768      // 3*H
#define NFRM  8
#define NCLS  2

// GRU chunking: CHUNK=32 payload, WARM=48 warmup, BQ=4 chunks/block.
#define CHUNK 32
#define WARM  48
#define GSTEPS (WARM + CHUNK)           // 80
#define BQ    4
#define NCHUNK (T_LEN / CHUNK)          // 512 per dir
#define GRU_BLOCKS (NCHUNK / BQ)        // 128 per dir

typedef _Float16 f16x8 __attribute__((ext_vector_type(8)));
typedef float    f32x4 __attribute__((ext_vector_type(4)));

// ---------------- workspace layout (in floats) ----------------
static const size_t OFF_GXF = 0;
static const size_t OFF_GXB = OFF_GXF + (size_t)T_LEN * G3;
static const size_t OFF_H   = OFF_GXB + (size_t)T_LEN * G3;
static const size_t OFF_BIA = OFF_H   + (size_t)T_LEN * 512;    // folded biases 2*768
static const size_t OFF_SC  = OFF_BIA + 2 * G3;
static const size_t OFF_WPF = OFF_SC  + (size_t)T_LEN;          // f16x8[48*8*64] = 393216 B
static const size_t OFF_WPB = OFF_WPF + (size_t)G3 * H_GRU / 2;
static const size_t OFF_SEL = OFF_WPB + (size_t)G3 * H_GRU / 2; // 8 int idx + 8 float w
static const size_t OFF_CH  = OFF_SEL + 16;                     // 256 floats hidden
static const size_t OFF_A16 = OFF_CH + 256;                     // fp16 features (optional)
static const size_t WS_NEED_A16 = OFF_A16 + (size_t)T_LEN * D_IN / 2; // floats
// base ~134 MB; +67 MB if A16 fits (runtime ws_size check, else exact-R0 fallback)
// NOTE: B16 (fp16 W_ih_cat, 1536x2048 = 6.3 MB) lives in the Hbuf region
// (ws + OFF_H) during the GEMM; Hbuf is only written by the GRU afterwards.

__device__ __forceinline__ float fsig(float x) {
    return __builtin_amdgcn_rcpf(1.f + __expf(-x));
}
__device__ __forceinline__ float ftanh(float x) {
    float e = __expf(2.f * x);
    return 1.f - 2.f * __builtin_amdgcn_rcpf(e + 1.f);
}

// ---------------- fold b_hh (r,z gates) into the input-projection bias ----------------
__global__ void bias_fold_kernel(const float* __restrict__ bi0, const float* __restrict__ bh0,
                                 const float* __restrict__ bi1, const float* __restrict__ bh1,
                                 float* __restrict__ o0, float* __restrict__ o1) {
    int t = blockIdx.x * 256 + threadIdx.x;
    if (t < G3) {
        float a0 = bi0[t], a1 = bi1[t];
        if (t < 512) { a0 += bh0[t]; a1 += bh1[t]; }
        o0[t] = a0; o1[t] = a1;
    }
}

// ---------------- convert W_ih_{f,b} (fp32) -> B16 fp16 [1536][2048] ----------------
__global__ __launch_bounds__(256) void cvt_w_kernel(const float* __restrict__ Wf,
                                                    const float* __restrict__ Wb,
                                                    __half* __restrict__ B16) {
    const float* __restrict__ src = blockIdx.y ? Wb : Wf;
    __half* __restrict__ dst = B16 + (size_t)blockIdx.y * G3 * D_IN;
    const int i = blockIdx.x * 256 + threadIdx.x;    // 8 floats per thread
    float4 a = *(const float4*)&src[(size_t)i * 8];
    float4 b = *(const float4*)&src[(size_t)i * 8 + 4];
    __half2 h[4];
    h[0] = __float22half2_rn(make_float2(a.x, a.y));
    h[1] = __float22half2_rn(make_float2(a.z, a.w));
    h[2] = __float22half2_rn(make_float2(b.x, b.y));
    h[3] = __float22half2_rn(make_float2(b.z, b.w));
    *(float4*)&dst[(size_t)i * 8] = *(float4*)h;
}

// ---------------- convert features (fp32) -> A16 fp16 [16384][2048] ----------------
__global__ __launch_bounds__(256) void cvt_a_kernel(const float* __restrict__ A,
                                                    __half* __restrict__ A16) {
    const size_t i = ((size_t)blockIdx.x * 256 + threadIdx.x) * 8;
    float4 a = *(const float4*)&A[i];
    float4 b = *(const float4*)&A[i + 4];
    __half2 h[4];
    h[0] = __float22half2_rn(make_float2(a.x, a.y));
    h[1] = __float22half2_rn(make_float2(a.z, a.w));
    h[2] = __float22half2_rn(make_float2(b.x, b.y));
    h[3] = __float22half2_rn(make_float2(b.z, b.w));
    *(float4*)&A16[i] = *(float4*)h;
}

// ---------------- pack W_hh into MFMA A-fragment order ----------------
__global__ void pack_whh_mfma_kernel(const float* __restrict__ W0,
                                     const float* __restrict__ W1,
                                     f16x8* __restrict__ P0,
                                     f16x8* __restrict__ P1) {
    const float* W = blockIdx.y ? W1 : W0;
    f16x8* P = blockIdx.y ? P1 : P0;
    int tc = blockIdx.x;             // 0..383 = t*8 + c
    int l = threadIdx.x;             // 0..63
    int t = tc >> 3, c = tc & 7;
    int m = t * 16 + (l & 15);
    int k = c * 32 + (l >> 4) * 8;
    const float* src = W + (size_t)m * H_GRU + k;
    f16x8 v;
#pragma unroll
    for (int j = 0; j < 8; ++j) v[j] = (_Float16)src[j];
    P[(size_t)tc * 64 + l] = v;
}

// ---------------- gx GEMM: EXACT R0 structure; only the operand dtype differs ----------------
// C[M][768] per dir = A @ W_ih^T + bias. 128x128 tile, BK=32, 4 waves,
// reg-staged LDS, two barriers per K-step — the proven-fastest structure
// (220us @ fp32 A). Staging geometry (srow=tid>>3, scol=(tid&7)*4) and the
// [128][32] __half LDS layout are IDENTICAL to R0 (its 8-way read conflicts
// were proven non-fatal; LDS is not the critical path). A16P=true swaps the
// float4 A load + in-loop cvt for a uint2 fp16 load (same rows, same cols,
// same LDS bytes) -> halves A traffic, deletes all in-loop cvts.
#define GM 128
#define GN 128
#define GK 32
template <bool A16P>
__global__ __launch_bounds__(256, 2) void gemm_f16_kernel(
    const float* __restrict__ A,      // features f32 (fallback path)
    const __half* __restrict__ A16,   // features f16 (fast path)
    const __half* __restrict__ B16,   // [1536][2048] f16 (dir-concat)
    const float* __restrict__ biaf, const float* __restrict__ biab,
    float* __restrict__ Cf, float* __restrict__ Cb) {
    __shared__ __align__(16) __half As[GM][GK];   // 8 KB
    __shared__ __align__(16) __half Bs[GN][GK];   // 8 KB

    const int tid  = threadIdx.x;
    const int lane = tid & 63;
    const int wave = tid >> 6;
    const int mw   = wave & 1;
    const int nw   = wave >> 1;
    const int lm   = lane & 15;
    const int lk   = lane >> 4;

    const int bm  = blockIdx.x * GM;
    const int bn  = blockIdx.y * GN;
    const int dir = blockIdx.z;
    const int bnt = dir * G3 + bn;          // row offset into B16 [0..1535]
    const float* __restrict__ bias = dir ? biab : biaf;
    float* __restrict__ C          = dir ? Cb  : Cf;

    const int srow = tid >> 3;              // 0..31
    const int scol = (tid & 7) * 4;         // 0,4,...,28 (elements)

    f32x4 acc[4][4];
#pragma unroll
    for (int a = 0; a < 4; ++a)
#pragma unroll
        for (int b = 0; b < 4; ++b) acc[a][b] = (f32x4)0.f;

    for (int k0 = 0; k0 < D_IN; k0 += GK) {
        float4 av[4];
        uint2  a16v[4], bv[4];
#pragma unroll
        for (int j = 0; j < 4; ++j) {
            if constexpr (A16P)
                a16v[j] = *(const uint2*)&A16[(size_t)(bm + 32 * j + srow) * D_IN + k0 + scol];
            else
                av[j] = *(const float4*)&A[(size_t)(bm + 32 * j + srow) * D_IN + k0 + scol];
            bv[j] = *(const uint2*)&B16[(size_t)(bnt + 32 * j + srow) * D_IN + k0 + scol];
        }
        __syncthreads();
#pragma unroll
        for (int j = 0; j < 4; ++j) {
            int r = 32 * j + srow;
            if constexpr (A16P) {
                *(uint2*)&As[r][scol] = a16v[j];
            } else {
                *((__half2*)&As[r][scol + 0]) = __float22half2_rn(make_float2(av[j].x, av[j].y));
                *((__half2*)&As[r][scol + 2]) = __float22half2_rn(make_float2(av[j].z, av[j].w));
            }
            *(uint2*)&Bs[r][scol] = bv[j];
        }
        __syncthreads();

        f16x8 afr[4], bfr[4];
#pragma unroll
        for (int tm = 0; tm < 4; ++tm)
            afr[tm] = *(const f16x8*)&As[64 * mw + 16 * tm + lm][lk * 8];
#pragma unroll
        for (int tn = 0; tn < 4; ++tn)
            bfr[tn] = *(const f16x8*)&Bs[64 * nw + 16 * tn + lm][lk * 8];
#pragma unroll
        for (int tm = 0; tm < 4; ++tm)
#pragma unroll
            for (int tn = 0; tn < 4; ++tn)
                acc[tm][tn] = __builtin_amdgcn_mfma_f32_16x16x32_f16(
                    afr[tm], bfr[tn], acc[tm][tn], 0, 0, 0);
    }

#pragma unroll
    for (int tm = 0; tm < 4; ++tm) {
#pragma unroll
        for (int tn = 0; tn < 4; ++tn) {
            int gn = bn + 64 * nw + 16 * tn + lm;
            float bb = bias[gn];
#pragma unroll
            for (int reg = 0; reg < 4; ++reg) {
                int gm = bm + 64 * mw + 16 * tm + lk * 4 + reg;
                C[(size_t)gm * G3 + gn] = acc[tm][tn][reg] + bb;
            }
        }
    }
}

// ---------------- scorer: scores = relu(Hbuf @ Ws1^T + bs1) @ Ws2^T + bs2 ----------------
// 64x64 tile over M, N=64 fixed (whole Ws1), layer-2 dot fused in epilogue.
#define BM 64
#define BN 64
#define BK 32
__global__ __launch_bounds__(256) void scorer_kernel(
    const float* __restrict__ A,       // Hbuf [T][512]
    const float* __restrict__ B,       // Ws1 [64][512]
    const float* __restrict__ bias,    // bs1 [64]
    const float* __restrict__ Ws2,     // [64]
    const float* __restrict__ bs2,     // [1]
    float* __restrict__ sc, float* __restrict__ outs,
    int M, int N, int K) {
    __shared__ __align__(16) float As[BK][BM + 4];
    __shared__ __align__(16) float Bs[BK][BN + 4];

    const int tid = threadIdx.x;
    const int bm = blockIdx.x * BM;
    const int kk8 = tid & 7;
    const int r32 = tid >> 3;
    const int tx = tid & 15;
    const int ty = tid >> 4;

    float acc[4][4];
#pragma unroll
    for (int a = 0; a < 4; ++a)
#pragma unroll
        for (int b = 0; b < 4; ++b) acc[a][b] = 0.f;

    for (int k0 = 0; k0 < K; k0 += BK) {
        float4 a0 = *(const float4*)&A[(size_t)(bm + r32) * K + k0 + kk8 * 4];
        float4 a1 = *(const float4*)&A[(size_t)(bm + r32 + 32) * K + k0 + kk8 * 4];
        float4 b0 = *(const float4*)&B[(size_t)(r32) * K + k0 + kk8 * 4];
        float4 b1 = *(const float4*)&B[(size_t)(r32 + 32) * K + k0 + kk8 * 4];
        __syncthreads();
        As[kk8 * 4 + 0][r32] = a0.x; As[kk8 * 4 + 1][r32] = a0.y;
        As[kk8 * 4 + 2][r32] = a0.z; As[kk8 * 4 + 3][r32] = a0.w;
        As[kk8 * 4 + 0][r32 + 32] = a1.x; As[kk8 * 4 + 1][r32 + 32] = a1.y;
        As[kk8 * 4 + 2][r32 + 32] = a1.z; As[kk8 * 4 + 3][r32 + 32] = a1.w;
        Bs[kk8 * 4 + 0][r32] = b0.x; Bs[kk8 * 4 + 1][r32] = b0.y;
        Bs[kk8 * 4 + 2][r32] = b0.z; Bs[kk8 * 4 + 3][r32] = b0.w;
        Bs[kk8 * 4 + 0][r32 + 32] = b1.x; Bs[kk8 * 4 + 1][r32 + 32] = b1.y;
        Bs[kk8 * 4 + 2][r32 + 32] = b1.z; Bs[kk8 * 4 + 3][r32 + 32] = b1.w;
        __syncthreads();
#pragma unroll 8
        for (int kk = 0; kk < BK; ++kk) {
            float4 av = *(const float4*)&As[kk][ty * 4];
            float4 bv = *(const float4*)&Bs[kk][tx * 4];
            acc[0][0] += av.x * bv.x; acc[0][1] += av.x * bv.y; acc[0][2] += av.x * bv.z; acc[0][3] += av.x * bv.w;
            acc[1][0] += av.y * bv.x; acc[1][1] += av.y * bv.y; acc[1][2] += av.y * bv.z; acc[1][3] += av.y * bv.w;
            acc[2][0] += av.z * bv.x; acc[2][1] += av.z * bv.y; acc[2][2] += av.z * bv.z; acc[2][3] += av.z * bv.w;
            acc[3][0] += av.w * bv.x; acc[3][1] += av.w * bv.y; acc[3][2] += av.w * bv.z; acc[3][3] += av.w * bv.w;
        }
    }

    // fused layer 2: per-thread partial dot over its 4 cols, reduce across tx group
    float4 bvv = *(const float4*)&bias[tx * 4];
    float4 w2  = *(const float4*)&Ws2[tx * 4];
    const float b2 = bs2[0];
#pragma unroll
    for (int im = 0; im < 4; ++im) {
        float s = fmaxf(acc[im][0] + bvv.x, 0.f) * w2.x
                + fmaxf(acc[im][1] + bvv.y, 0.f) * w2.y
                + fmaxf(acc[im][2] + bvv.z, 0.f) * w2.z
                + fmaxf(acc[im][3] + bvv.w, 0.f) * w2.w;
#pragma unroll
        for (int off = 1; off < 16; off <<= 1) s += __shfl_xor(s, off);
        if (tx == 0) {
            int m = bm + ty * 4 + im;
            float sval = s + b2;
            sc[m] = sval;
            outs[m] = sval;
        }
    }
}

// ---------------- chunked BiGRU v5: W-resident MFMA, 1024-thread blocks ----------------
// 16 waves, wave wv owns 3 row-tiles (48 gate rows) of W in registers (96 VGPRs).
// Epilogue: thread (grp=tid>>8, i=tid&255) owns chunk grp, row i (1 state/thread).
#define HPAD 272
__global__ __launch_bounds__(1024, 4) void gru_v5_kernel(
    const float* __restrict__ gx0, const float* __restrict__ gx1,
    const f16x8* __restrict__ Wk0, const f16x8* __restrict__ Wk1,
    const float* __restrict__ bh0, const float* __restrict__ bh1,
    float* __restrict__ Hbuf) {
    const int dir = blockIdx.y;
    const float* __restrict__ gx = dir ? gx1 : gx0;
    const f16x8* __restrict__ Wk = dir ? Wk1 : Wk0;
    const float* __restrict__ bh = dir ? bh1 : bh0;
    const int col_off = dir * 256;

    const int tid  = threadIdx.x;
    const int lane = tid & 63;
    const int wv   = tid >> 6;       // wave 0..15
    const int ln   = lane & 15;      // MFMA col (chunk) index
    const int lq   = lane >> 4;      // quad 0..3

    __shared__ __align__(16) __half h_sh[16][HPAD];   // rows 0..3 = chunks, rest zero
    __shared__ __align__(16) float red[4][772];       // gates [chunk][768]

    // W fragments: 3 tiles x 8 k-chunks, resident (96 VGPRs/AGPRs)
    f16x8 Wf[3][8];
#pragma unroll
    for (int tt = 0; tt < 3; ++tt)
#pragma unroll
        for (int c = 0; c < 8; ++c)
            Wf[tt][c] = Wk[(size_t)((3 * wv + tt) * 8 + c) * 64 + lane];

    for (int idx = tid; idx < 16 * HPAD; idx += 1024) ((__half*)h_sh)[idx] = __float2half(0.f);

    const int i   = tid & 255;
    const int grp = tid >> 8;        // chunk 0..3
    const float bn_ = bh[512 + i];   // b_hh n-gate (r,z folded into gx)
    float h_own = 0.f;
    const int cbase = blockIdx.x * BQ;
    const int dtv = dir ? -1 : 1;
    const int lo = (cbase + grp) * CHUNK;
    const int t0 = dir ? (lo + CHUNK - 1 + WARM) : (lo - WARM);
    __syncthreads();

    for (int s = 0; s < GSTEPS; ++s) {
        const int t = t0 + dtv * s;
        const bool valid = ((unsigned)t < (unsigned)T_LEN);
        const int tc2 = t < 0 ? 0 : (t > T_LEN - 1 ? T_LEN - 1 : t);
        const float* g = gx + (size_t)tc2 * G3 + i;
        const float xr = g[0], xz = g[256], xn = g[512];

        f32x4 acc[3];
#pragma unroll
        for (int tt = 0; tt < 3; ++tt) acc[tt] = (f32x4)0.f;
#pragma unroll
        for (int c = 0; c < 8; ++c) {
            f16x8 bfr = *(const f16x8*)&h_sh[ln][c * 32 + lq * 8];
#pragma unroll
            for (int tt = 0; tt < 3; ++tt)
                acc[tt] = __builtin_amdgcn_mfma_f32_16x16x32_f16(Wf[tt][c], bfr, acc[tt], 0, 0, 0);
        }
        if (ln < 4) {
#pragma unroll
            for (int tt = 0; tt < 3; ++tt)
                *(f32x4*)&red[ln][(3 * wv + tt) * 16 + lq * 4] = acc[tt];
        }
        __syncthreads();   // gates visible; h reads done

        const float r = fsig(xr + red[grp][i]);
        const float z = fsig(xz + red[grp][256 + i]);
        const float nn = ftanh(xn + r * (red[grp][512 + i] + bn_));
        const float hnew = (1.f - z) * nn + z * h_own;
        if (valid) {
            h_own = hnew;
            h_sh[grp][i] = __float2half(hnew);
            const bool pay = dir ? (t < lo + CHUNK) : (t >= lo);
            if (pay) Hbuf[(size_t)t * 512 + col_off + i] = hnew;
        }
        __syncthreads();   // new h visible before next step's B-frag reads
    }
}

// ---------------- select: top-8 + softmax weights (register-resident scan) ----------------
__global__ __launch_bounds__(256) void select_topk_kernel(
    const float* __restrict__ scores, const float* __restrict__ temp_p,
    int* __restrict__ sel_idx_out, float* __restrict__ sel_w_out) {
    __shared__ float red_v[4];
    __shared__ int   red_i[4];
    __shared__ int   bcast_idx;
    __shared__ int   sel_idx_sh[NFRM];
    __shared__ float sel_v_sh[NFRM];

    const int tid  = threadIdx.x;
    const int lane = tid & 63;
    const int wv   = tid >> 6;

    float sv[64];
#pragma unroll
    for (int a = 0; a < 64; ++a) sv[a] = scores[a * 256 + tid];

    for (int round = 0; round < NFRM; ++round) {
        float best = -1e30f;
        int bidx = 0x7fffffff;
#pragma unroll
        for (int a = 0; a < 64; ++a) {
            if (sv[a] > best) { best = sv[a]; bidx = a * 256 + tid; }
        }
#pragma unroll
        for (int off = 32; off > 0; off >>= 1) {
            float v2 = __shfl_down(best, off);
            int   i2 = __shfl_down(bidx, off);
            if (v2 > best || (v2 == best && i2 < bidx)) { best = v2; bidx = i2; }
        }
        if (lane == 0) { red_v[wv] = best; red_i[wv] = bidx; }
        __syncthreads();
        if (tid == 0) {
            float bv = red_v[0]; int bi = red_i[0];
#pragma unroll
            for (int w = 1; w < 4; ++w)
                if (red_v[w] > bv || (red_v[w] == bv && red_i[w] < bi)) { bv = red_v[w]; bi = red_i[w]; }
            sel_idx_sh[round] = bi; sel_v_sh[round] = bv; bcast_idx = bi;
        }
        __syncthreads();
        const int widx = bcast_idx;
        if ((widx & 255) == tid) {
            const int aa = widx >> 8;
#pragma unroll
            for (int a = 0; a < 64; ++a)
                if (a == aa) sv[a] = -1e30f;
        }
    }

    if (tid == 0) {
        float temp = temp_p[0];
        float m = sel_v_sh[0];
        float e[NFRM];
        float sum = 0.f;
        for (int j = 0; j < NFRM; ++j) { e[j] = expf((sel_v_sh[j] - m) / temp); sum += e[j]; }
        for (int j = 0; j < NFRM; ++j) { sel_idx_out[j] = sel_idx_sh[j]; sel_w_out[j] = e[j] / sum; }
    }
}

// ---------------- classifier layer 1: 256 blocks, one hidden row each ----------------
__global__ __launch_bounds__(256) void classifier1_kernel(
    const float* __restrict__ features,
    const int* __restrict__ sel_idx, const float* __restrict__ sel_w,
    const float* __restrict__ Wc1, const float* __restrict__ bc1,
    float* __restrict__ hid) {
    const int r = blockIdx.x;
    const int tid = threadIdx.x;
    __shared__ int   s_idx[NFRM];
    __shared__ float s_w[NFRM];
    __shared__ float part[4];
    if (tid < NFRM) { s_idx[tid] = sel_idx[tid]; s_w[tid] = sel_w[tid]; }
    __syncthreads();

    float acc = 0.f;
#pragma unroll
    for (int q = 0; q < D_IN / 256; ++q) {
        int d = q * 256 + tid;
        float c = 0.f;
#pragma unroll
        for (int j = 0; j < NFRM; ++j)
            c += s_w[j] * features[(size_t)s_idx[j] * D_IN + d];
        acc += c * Wc1[(size_t)r * D_IN + d];
    }
#pragma unroll
    for (int off = 32; off > 0; off >>= 1) acc += __shfl_down(acc, off);
    if ((tid & 63) == 0) part[tid >> 6] = acc;
    __syncthreads();
    if (tid == 0)
        hid[r] = fmaxf(part[0] + part[1] + part[2] + part[3] + bc1[r], 0.f);
}

// ---------------- classifier layer 2: logits ----------------
__global__ __launch_bounds__(128) void classifier2_kernel(
    const float* __restrict__ hid, const float* __restrict__ Wc2,
    const float* __restrict__ bc2, float* __restrict__ out) {
    const int tid = threadIdx.x;
    const int c = tid >> 6;
    const int l = tid & 63;
    float acc = 0.f;
#pragma unroll
    for (int k = l; k < 256; k += 64) acc += hid[k] * Wc2[c * 256 + k];
#pragma unroll
    for (int off = 32; off > 0; off >>= 1) acc += __shfl_down(acc, off);
    if (l == 0) out[c] = acc + bc2[c];
}

// ---------------- launcher ----------------
extern "C" void kernel_launch(void* const* d_in, const int* in_sizes, int n_in,
                              void* d_out, int out_size, void* d_ws, size_t ws_size,
                              hipStream_t stream) {
    const float* features = (const float*)d_in[0];
    const float* temperature = (const float*)d_in[1];
    const float* W_ih_f = (const float*)d_in[2];
    const float* W_hh_f = (const float*)d_in[3];
    const float* b_ih_f = (const float*)d_in[4];
    const float* b_hh_f = (const float*)d_in[5];
    const float* W_ih_b = (const float*)d_in[6];
    const float* W_hh_b = (const float*)d_in[7];
    const float* b_ih_b = (const float*)d_in[8];
    const float* b_hh_b = (const float*)d_in[9];
    const float* Ws1 = (const float*)d_in[10];
    const float* bs1 = (const float*)d_in[11];
    const float* Ws2 = (const float*)d_in[12];
    const float* bs2 = (const float*)d_in[13];
    const float* Wc1 = (const float*)d_in[14];
    const float* bc1 = (const float*)d_in[15];
    const float* Wc2 = (const float*)d_in[16];
    const float* bc2 = (const float*)d_in[17];

    float* ws = (float*)d_ws;
    float* gx_f = ws + OFF_GXF;
    float* gx_b = ws + OFF_GXB;
    float* Hbuf = ws + OFF_H;
    float* biaf = ws + OFF_BIA;
    float* biab = ws + OFF_BIA + G3;
    float* sc   = ws + OFF_SC;
    f16x8* Wk_f = (f16x8*)(ws + OFF_WPF);
    f16x8* Wk_b = (f16x8*)(ws + OFF_WPB);
    int*   sel_i = (int*)(ws + OFF_SEL);
    float* sel_w = ws + OFF_SEL + NFRM;
    float* chid  = ws + OFF_CH;
    float* out  = (float*)d_out;

    // B16 borrows the Hbuf region (dead until the GRU runs)
    __half* B16 = (__half*)(ws + OFF_H);
    // A16 (optional) at the end of the workspace
    __half* A16 = (__half*)(ws + OFF_A16);
    const bool useA16 = (ws_size >= WS_NEED_A16 * sizeof(float));

    // fold b_hh(r,z) into input-projection bias
    bias_fold_kernel<<<3, 256, 0, stream>>>(b_ih_f, b_hh_f, b_ih_b, b_hh_b, biaf, biab);

    // convert input-projection weights to fp16 (both dirs concatenated)
    cvt_w_kernel<<<dim3(768, 2), 256, 0, stream>>>(W_ih_f, W_ih_b, B16);

    // pack recurrent weights into MFMA fragment order
    pack_whh_mfma_kernel<<<dim3(384, 2), 64, 0, stream>>>(W_hh_f, W_hh_b, Wk_f, Wk_b);

    // gx_{f,b} = features @ W_ih^T + (b_ih + b_hh[r,z])  (exact R0 GEMM; fp16 A if ws fits)
    if (useA16) {
        cvt_a_kernel<<<T_LEN * D_IN / 8 / 256, 256, 0, stream>>>(features, A16);
        gemm_f16_kernel<true><<<dim3(T_LEN / GM, G3 / GN, 2), 256, 0, stream>>>(
            features, A16, B16, biaf, biab, gx_f, gx_b);
    } else {
        gemm_f16_kernel<false><<<dim3(T_LEN / GM, G3 / GN, 2), 256, 0, stream>>>(
            features, A16, B16, biaf, biab, gx_f, gx_b);
    }

    // chunked BiGRU v5 (W-resident MFMA, 1024-thread blocks)
    gru_v5_kernel<<<dim3(GRU_BLOCKS, 2), 1024, 0, stream>>>(
        gx_f, gx_b, Wk_f, Wk_b, b_hh_f, b_hh_b, Hbuf);

    // fused scorer (layer1 GEMM + layer2 dot) -> scores
    scorer_kernel<<<T_LEN / BM, 256, 0, stream>>>(
        Hbuf, Ws1, bs1, Ws2, bs2, sc, out + 2, T_LEN, 64, 512);

    // top-8 + softmax weights
    select_topk_kernel<<<1, 256, 0, stream>>>(sc, temperature, sel_i, sel_w);

    // classifier layer 1 (parallel over rows, clip computed on the fly)
    classifier1_kernel<<<256, 256, 0, stream>>>(features, sel_i, sel_w, Wc1, bc1, chid);

    // classifier layer 2 -> logits
    classifier2_kernel<<<1, 128, 0, stream>>>(chid, Wc2, bc2, out);
}